// Round 14
// baseline (8512.643 us; speedup 1.0000x reference)
//
#include <hip/hip_runtime.h>
#include <hip/hip_bf16.h>
#include <math.h>

using bf16 = __hip_bfloat16;
typedef __attribute__((ext_vector_type(8))) short s16x8;   // 8 bf16 = 4 VGPR
typedef __attribute__((ext_vector_type(4))) float f32x4;

struct __align__(16) B8 { bf16 v[8]; };
struct __align__(8)  B4 { bf16 v[4]; };

__device__ __forceinline__ float b2f(bf16 x){ return __bfloat162float(x); }
__device__ __forceinline__ bf16  f2b(float x){ return __float2bfloat16(x); }

enum { EPI_QKV=0, EPI_AO=3, EPI_FC=4, EPI_PRB=5, EPI_OUT=6 };

#define SCHED0 __builtin_amdgcn_sched_barrier(0)
#define PRIO1  __builtin_amdgcn_s_setprio(1)
#define PRIO0  __builtin_amdgcn_s_setprio(0)
#define BAR    __builtin_amdgcn_s_barrier()
#define VM4    asm volatile("s_waitcnt vmcnt(4)" ::: "memory")
#define VM2    asm volatile("s_waitcnt vmcnt(2)" ::: "memory")
#define VM0    asm volatile("s_waitcnt vmcnt(0)" ::: "memory")
#define LGKM0  asm volatile("s_waitcnt lgkmcnt(0)" ::: "memory")
#define AS1    const __attribute__((address_space(1))) void*
#define AS3    __attribute__((address_space(3))) void*

// ============================================================================
// R14: 8-phase GEMM at 64 KB LDS -> 2 blocks/CU (m114 inter-block overlap).
// BM=BN=256, BK=64, 8 waves (2Mx4N), per-wave C = 128x64 as 2x2 quadrants.
// LDS = [2 half][128][64] per operand (NO dbuf).  Stages at half-granularity
// into the slot freed one phase earlier:
//   p1: reads Bh0,Ah0 ............ VM2 (retire Bh1(t), staged p3(t-1))
//   p2: reads Bh1; STG Ah0(t+1) .. VM2 (retire Ah1(t), staged p4(t-1))
//   p3: reads Ah1; STG Bh0,Bh1(t+1)
//   p4: STG Ah1(t+1) ............. VM4 (retire Ah0,Bh0(t+1))
// Every staged half is >=2 phases old at its wait.  Slot-safety: each stage
// issues after the BAR closing the phase with the slot's last reads; every
// wave LGKM0-drains its own reads before that BAR.  In-flight <= 8.
// Requires M%256==0, N%256==0, K%64==0, NT>=2.
// ============================================================================
template<int EPI>
__launch_bounds__(512, 4)
__global__ void gemm256(const bf16* __restrict__ A, const bf16* __restrict__ B,
                        void* __restrict__ Cv, const float* __restrict__ bias,
                        const void* __restrict__ res,
                        int K, int lda, int ldb, int ldc, int ldres, int nbx)
{
    extern __shared__ __align__(16) bf16 lds[];
    bf16* Asl = lds;            // [2][128][64] = 32 KB
    bf16* Bsl = lds + 16384;    // [2][128][64] = 32 KB

    const int nwg = (int)gridDim.x;
    int wg = (int)blockIdx.x;
    if ((nwg & 7) == 0) wg = (wg & 7)*(nwg >> 3) + (wg >> 3);
    const int bx = wg % nbx, by = wg / nbx;
    const long m0 = (long)by*256, n0 = (long)bx*256;

    if constexpr (EPI==EPI_OUT){       // split-K: slice along K by blockIdx.y
        const long ko = (long)blockIdx.y * K;
        A += ko; B += ko;
        Cv = (void*)((float*)Cv + (long)blockIdx.y * 4194304);  // 8192*512
    }

    const int tid = threadIdx.x, wave = tid>>6, lane = tid&63;
    const int wr = wave>>2, wc = wave&3;          // 2 x 4 wave grid
    const int NT = K>>6;                          // K-tiles of 64 (>=2)
    const int fr = lane&15, fg = lane>>4;

    // fragment read bases; chunk swizzle ck = (kk*4+fg) ^ (fr&7) (thread-const)
    const int ck0 = fg ^ (fr&7);
    const int ck1 = (4+fg) ^ (fr&7);
    const bf16* aRd0 = Asl + wr*4096 + fr*64 + ck0*8;
    const bf16* aRd1 = Asl + wr*4096 + fr*64 + ck1*8;
    const bf16* bRd0 = Bsl + wc*2048 + fr*64 + ck0*8;
    const bf16* bRd1 = Bsl + wc*2048 + fr*64 + ck1*8;

    #define RDA(rh) { _Pragma("unroll") for (int i=0;i<4;++i){ \
        a[i][0] = *(const s16x8*)(aRd0 + (rh)*8192 + i*1024); \
        a[i][1] = *(const s16x8*)(aRd1 + (rh)*8192 + i*1024); } }
    #define RDB(dst, ch) { _Pragma("unroll") for (int j=0;j<2;++j){ \
        dst[j][0] = *(const s16x8*)(bRd0 + (ch)*8192 + j*1024); \
        dst[j][1] = *(const s16x8*)(bRd1 + (ch)*8192 + j*1024); } }

    // staging: half-tile = 128 rows x 64 k = 16 KB = 2 loads/thread.
    const int grow = tid>>3;
    const int gc0  = (tid&7) ^ (grow&7);
    const bf16* aP = A + (m0 + grow)*(long)lda + gc0*8;
    const bf16* bP = B + (n0 + grow)*(long)ldb + gc0*8;

    #define STGA(sh, koff) { _Pragma("unroll") for (int l=0;l<2;++l) \
        __builtin_amdgcn_global_load_lds((AS1)(aP + ((sh)*128 + l*64)*(long)lda + (koff)), \
            (AS3)(Asl + (sh)*8192 + l*4096 + wave*512 + lane*8), 16, 0, 0); }
    #define STGB(sh, koff) { _Pragma("unroll") for (int l=0;l<2;++l) \
        __builtin_amdgcn_global_load_lds((AS1)(bP + ((sh)*128 + l*64)*(long)ldb + (koff)), \
            (AS3)(Bsl + (sh)*8192 + l*4096 + wave*512 + lane*8), 16, 0, 0); }

    f32x4 acc[2][4][2][2];
    #pragma unroll
    for (int rh=0;rh<2;++rh)
        #pragma unroll
        for (int i=0;i<4;++i)
            #pragma unroll
            for (int ch=0;ch<2;++ch)
                #pragma unroll
                for (int j=0;j<2;++j)
                    #pragma unroll
                    for (int r=0;r<4;++r) acc[rh][i][ch][j][r] = 0.f;

    #define MM(rh, ch, BB) { PRIO1; \
        _Pragma("unroll") for (int i=0;i<4;++i) \
        _Pragma("unroll") for (int j=0;j<2;++j) \
        _Pragma("unroll") for (int kk=0;kk<2;++kk) \
            acc[rh][i][ch][j] = __builtin_amdgcn_mfma_f32_16x16x32_bf16(a[i][kk], BB[j][kk], acc[rh][i][ch][j], 0,0,0); \
        PRIO0; }

    s16x8 a[4][2], b0[2][2], b1[2][2];

    // ---- prologue: tile0 = Ah0,Bh0,Bh1,Ah1 (8 loads); retire Ah0,Bh0
    STGA(0,0); STGB(0,0); STGB(1,0); STGA(1,0);
    VM4; BAR;                // remaining in flight: [Bh1(0), Ah1(0)]

    for (int t=0; t<NT-1; ++t){
        // p1: reads Bh0,Ah0(t)
        RDB(b0,0); RDA(0);
        VM2;                          // retire Bh1(t)
        BAR; LGKM0; MM(0,0,b0); BAR;
        // p2: reads Bh1(t); stage Ah0(t+1)
        RDB(b1,1);
        STGA(0, 64);
        VM2;                          // retire Ah1(t)
        BAR; LGKM0; MM(0,1,b1); BAR;
        // p3: reads Ah1(t); stage Bh0,Bh1(t+1)
        RDA(1);
        STGB(0, 64); STGB(1, 64);
        BAR; LGKM0; MM(1,1,b1); BAR;
        // p4: stage Ah1(t+1); retire Ah0,Bh0(t+1)
        STGA(1, 64);
        VM4;
        BAR; LGKM0; MM(1,0,b0); BAR;
        aP += 64; bP += 64;
    }

    // ---- tail tile NT-1 (no stages)
    RDB(b0,0); RDA(0);
    VM2;                              // retire Bh1
    BAR; LGKM0; MM(0,0,b0); BAR;
    RDB(b1,1);
    VM0;                              // retire Ah1
    BAR; LGKM0; MM(0,1,b1); BAR;
    RDA(1);
    BAR; LGKM0; MM(1,1,b1); BAR;
    MM(1,0,b0);

    #undef RDA
    #undef RDB
    #undef STGA
    #undef STGB
    #undef MM

    // ---- epilogue: C row = m0+rh*128+wr*64+i*16+fg*4+r, col = n0+ch*128+wc*32+j*16+fr
    const bool vmode = (n0 >= 4096);          // used only by EPI_QKV (block-uniform)
    bf16* vtp = (bf16*)res;                   // EPI_QKV: vt base
    #pragma unroll
    for (int rh=0;rh<2;++rh)
        #pragma unroll
        for (int i=0;i<4;++i){
            const long mmb = m0 + rh*128 + wr*64 + i*16 + fg*4;
            #pragma unroll
            for (int ch=0;ch<2;++ch)
                #pragma unroll
                for (int j=0;j<2;++j){
                    const long nn = n0 + ch*128 + wc*32 + j*16 + fr;
                    if constexpr (EPI==EPI_QKV){
                        if (vmode){
                            B4 o;
                            #pragma unroll
                            for (int r=0;r<4;++r) o.v[r] = f2b(acc[rh][i][ch][j][r] + bias[nn]);
                            *reinterpret_cast<B4*>(vtp + (((mmb>>11)<<2) + ((nn-4096)>>9))*1048576
                                                   + (nn&511)*2048 + (mmb&2047)) = o;
                        } else {
                            #pragma unroll
                            for (int r=0;r<4;++r)
                                ((bf16*)Cv)[(mmb+r)*ldc + nn] = f2b(acc[rh][i][ch][j][r] + bias[nn]);
                        }
                    } else if constexpr (EPI==EPI_AO){
                        #pragma unroll
                        for (int r=0;r<4;++r)
                            ((bf16*)Cv)[(mmb+r)*ldc + nn] =
                                f2b(acc[rh][i][ch][j][r] + bias[nn] + ((const float*)res)[(mmb+r)*ldres + nn]);
                    } else if constexpr (EPI==EPI_PRB){
                        #pragma unroll
                        for (int r=0;r<4;++r)
                            ((bf16*)Cv)[(mmb+r)*ldc + nn] =
                                f2b(acc[rh][i][ch][j][r] + bias[nn] + b2f(((const bf16*)res)[(mmb+r)*ldres + nn]));
                    } else if constexpr (EPI==EPI_FC){
                        #pragma unroll
                        for (int r=0;r<4;++r){
                            const float tt = acc[rh][i][ch][j][r] + bias[nn];
                            const float g = 0.5f*tt*(1.f + tanhf(0.7978845608028654f*(tt + 0.044715f*tt*tt*tt)));
                            ((bf16*)Cv)[(mmb+r)*ldc + nn] = f2b(g);
                        }
                    } else { // EPI_OUT
                        #pragma unroll
                        for (int r=0;r<4;++r)
                            ((float*)Cv)[(mmb+r)*ldc + nn] = acc[rh][i][ch][j][r];  // bias in kred
                    }
                }
        }
}

// split-K reduce for OUT: out[r*2560+2048+c] = sum_4 partials + bias[c]
__launch_bounds__(256)
__global__ void kred(const float* __restrict__ p, const float* __restrict__ bias,
                     float* __restrict__ outp){
    const long idx = ((long)blockIdx.x*256 + threadIdx.x)*4;   // over 8192*512
    const long r = idx>>9, c = idx&511;
    float4 s0 = *(const float4*)&p[idx];
    const float4 s1 = *(const float4*)&p[idx + 4194304];
    const float4 s2 = *(const float4*)&p[idx + 8388608];
    const float4 s3 = *(const float4*)&p[idx + 12582912];
    const float4 bb = *(const float4*)&bias[c];
    s0.x += s1.x+s2.x+s3.x+bb.x; s0.y += s1.y+s2.y+s3.y+bb.y;
    s0.z += s1.z+s2.z+s3.z+bb.z; s0.w += s1.w+s2.w+s3.w+bb.w;
    *(float4*)&outp[r*2560 + 2048 + c] = s0;
}

// ============================================================================
// Fused causal flash-attention (R9-verified, untouched).
// ============================================================================
__launch_bounds__(512, 2)
__global__ void fattn(const bf16* __restrict__ qkv, const bf16* __restrict__ vt,
                      bf16* __restrict__ outp)
{
    extern __shared__ __align__(16) bf16 sh[];
    bf16* sQ = sh;                    // [64][512] swz(row&7)      64 KB
    bf16* sK = sh + 32768;            // 3 slots [128][64] swz     48 KB
    bf16* sP = sh + 57344;            // [64][128] swz(rl&15)      16 KB
    bf16* sV = sh + 65536;            // 2 bufs [256][32] swz      32 KB
    float* part = (float*)(sh + 32768);   // alias sK (dead at epilogue)

    const int bid = blockIdx.x;
    const int xcd = bid&7, t5 = bid>>3, rnd = t5>>5, ci = t5&31;
    const int bh = xcd*2 + rnd, b = bh>>2, h = bh&3;
    const int ib = 31 - ci;
    const int njb = (ib>>1) + 1;
    const int tid = threadIdx.x, wave = tid>>6, lane = tid&63;
    const int wr = wave>>2, wc = wave&3;
    const int fr = lane&15, fg = lane>>4;

    const bf16* Qg = qkv + ((long)b*2048 + ib*64)*6144 + h*512;
    const bf16* Kg = qkv + (long)b*2048*6144 + 2048 + h*512;
    const bf16* Vtb = vt + (long)bh*1048576;
    const float SCALE = 0.044194173824159216f;

    #define STGQ { _Pragma("unroll") for (int l=0;l<8;++l){                          \
        const int row = l*8 + (tid>>6);                                              \
        const int c   = (tid&63) ^ (row&7);                                          \
        __builtin_amdgcn_global_load_lds((AS1)(Qg + (long)row*6144 + c*8),           \
            (AS3)(sQ + l*4096 + wave*512 + lane*8), 16,0,0); } }
    #define STGK(slot, ec, KJ) { _Pragma("unroll") for (int l=0;l<2;++l){            \
        const int row = l*64 + (tid>>3);                                             \
        const int c   = (tid&7) ^ (row&7);                                           \
        __builtin_amdgcn_global_load_lds((AS1)((KJ) + (long)row*6144 + (ec)*64 + c*8),\
            (AS3)(sK + (slot)*8192 + l*4096 + wave*512 + lane*8), 16,0,0); } }
    #define STGV(buf, kf, eh, VJ) { _Pragma("unroll") for (int l=0;l<2;++l){         \
        const int row = l*128 + (tid>>2);                                            \
        const int c   = (tid&3) ^ ((row + (row>>2))&3);                              \
        __builtin_amdgcn_global_load_lds((AS1)((VJ) + (long)((eh)*256+row)*2048 + (kf)*32 + c*8),\
            (AS3)(sV + (buf)*8192 + l*4096 + wave*512 + lane*8), 16,0,0); } }

    f32x4 acc[2][8];
    #pragma unroll
    for (int m=0;m<2;++m)
        #pragma unroll
        for (int j=0;j<8;++j)
            #pragma unroll
            for (int r=0;r<4;++r) acc[m][j][r] = 0.f;
    float l_l[2][4];
    #pragma unroll
    for (int m=0;m<2;++m){ l_l[m][0]=0.f; l_l[m][1]=0.f; l_l[m][2]=0.f; l_l[m][3]=0.f; }

    const bf16* KgJ = Kg;
    const bf16* VtJ = Vtb;

    STGQ;
    STGK(0, 0, KgJ);
    STGK(1, 1, KgJ);
    VM2; SCHED0; BAR;

    for (int jb=0; jb<njb; ++jb){
        const bool last = (jb == njb-1);
        f32x4 sacc[2][2];
        #pragma unroll
        for (int m=0;m<2;++m)
            #pragma unroll
            for (int nf=0;nf<2;++nf)
                #pragma unroll
                for (int r=0;r<4;++r) sacc[m][nf][r] = 0.f;

        #pragma unroll
        for (int ec=0; ec<8; ++ec){
            const int slot = ec%3;
            s16x8 qa[2][2], kb[2][2];
            #pragma unroll
            for (int m=0;m<2;++m)
                #pragma unroll
                for (int kk=0;kk<2;++kk){
                    const int row = wr*32 + m*16 + fr;
                    const int c = (ec*2+kk)*4 + fg;
                    qa[m][kk] = *(const s16x8*)(sQ + row*512 + ((c ^ (row&7))*8));
                }
            #pragma unroll
            for (int nf=0;nf<2;++nf)
                #pragma unroll
                for (int kk=0;kk<2;++kk){
                    const int row = wc*32 + nf*16 + fr;
                    const int c = kk*4 + fg;
                    kb[nf][kk] = *(const s16x8*)(sK + slot*8192 + row*64 + ((c ^ (row&7))*8));
                }
            if (ec < 6) STGK((ec+2)%3, ec+2, KgJ);
            PRIO1;
            #pragma unroll
            for (int m=0;m<2;++m)
                #pragma unroll
                for (int nf=0;nf<2;++nf)
                    #pragma unroll
                    for (int kk=0;kk<2;++kk)
                        sacc[m][nf] = __builtin_amdgcn_mfma_f32_16x16x32_bf16(qa[m][kk], kb[nf][kk], sacc[m][nf], 0,0,0);
            PRIO0;
            if (ec < 6) { VM2; } else if (ec == 6) { VM0; }
            SCHED0; BAR;
        }

        const int doff = (njb-1)*128 - ib*64;
        #pragma unroll
        for (int m=0;m<2;++m)
            #pragma unroll
            for (int nf=0;nf<2;++nf)
                #pragma unroll
                for (int r=0;r<4;++r){
                    float pv = __expf(sacc[m][nf][r]*SCALE - 4.0f);
                    const int rl = wr*32 + m*16 + fg*4 + r;
                    const int cl = wc*32 + nf*16 + fr;
                    if (last && (cl + doff > rl)) pv = 0.f;
                    sP[rl*128 + (((cl>>3) ^ (rl&15))*8) + (cl&7)] = f2b(pv);
                    l_l[m][r] += pv;
                }
        STGV(0, 0, 0, VtJ);
        if (!last){ STGK(0, 0, KgJ + 786432); STGK(1, 1, KgJ + 786432); }
        if (!last){ VM4; } else { VM0; }
        LGKM0; SCHED0; BAR;

        s16x8 pa[2];
        #pragma unroll
        for (int v=0; v<8; ++v){
            const int kf = v>>1, eh = v&1, buf = v&1;
            if (eh == 0){
                #pragma unroll
                for (int m=0;m<2;++m){
                    const int row = wr*32 + m*16 + fr;
                    const int c = kf*4 + fg;
                    pa[m] = *(const s16x8*)(sP + row*128 + ((c ^ (row&15))*8));
                }
            }
            s16x8 vb[4];
            #pragma unroll
            for (int nf=0;nf<4;++nf){
                const int row = wc*64 + nf*16 + fr;
                vb[nf] = *(const s16x8*)(sV + buf*8192 + row*32 + (((fg ^ ((row + (row>>2))&3)))*8));
            }
            if (v < 7) STGV((v+1)&1, (v+1)>>1, (v+1)&1, VtJ);
            PRIO1;
            #pragma unroll
            for (int m=0;m<2;++m)
                #pragma unroll
                for (int nf=0;nf<4;++nf)
                    acc[m][eh*4+nf] = __builtin_amdgcn_mfma_f32_16x16x32_bf16(pa[m], vb[nf], acc[m][eh*4+nf], 0,0,0);
            PRIO0;
            if (v < 7) { VM0; }
            SCHED0; BAR;
        }
        KgJ += 786432;
        VtJ += 128;
    }

    #pragma unroll
    for (int m=0;m<2;++m)
        #pragma unroll
        for (int r=0;r<4;++r){
            float v = l_l[m][r];
            v += __shfl_xor(v, 1); v += __shfl_xor(v, 2);
            v += __shfl_xor(v, 4); v += __shfl_xor(v, 8);
            l_l[m][r] = v;
        }
    if (fr == 0){
        #pragma unroll
        for (int m=0;m<2;++m)
            #pragma unroll
            for (int r=0;r<4;++r)
                part[(wr*32 + m*16 + fg*4 + r)*4 + wc] = l_l[m][r];
    }
    LGKM0; SCHED0; BAR;

    bf16* orow = outp + ((long)b*2048 + ib*64)*2048 + h*512;
    #pragma unroll
    for (int m=0;m<2;++m)
        #pragma unroll
        for (int r=0;r<4;++r){
            const int rl = wr*32 + m*16 + fg*4 + r;
            const f32x4 pp = *(const f32x4*)(part + rl*4);
            const float rinv = 1.f/(pp[0]+pp[1]+pp[2]+pp[3]);
            #pragma unroll
            for (int j=0;j<8;++j){
                const int e = (j>>2)*256 + wc*64 + (j&3)*16 + fr;
                orow[(long)rl*2048 + e] = f2b(acc[m][j][r]*rinv);
            }
        }
    #undef STGQ
    #undef STGK
    #undef STGV
}

// fp32 [Kd,Nd] -> bf16 [Nd,Kd]
__launch_bounds__(256)
__global__ void wtrans(const float* __restrict__ W, bf16* __restrict__ Wt, int Kd, int Nd){
    __shared__ float t[32][33];
    const int n0 = blockIdx.x*32, k0 = blockIdx.y*32;
    const int tx = threadIdx.x&31, ty = threadIdx.x>>5;
    #pragma unroll
    for (int i=0;i<32;i+=8) t[ty+i][tx] = W[(long)(k0+ty+i)*Nd + n0+tx];
    __syncthreads();
    #pragma unroll
    for (int i=0;i<32;i+=8) Wt[(long)(n0+ty+i)*Kd + k0+tx] = f2b(t[tx][ty+i]);
}

// x read ONCE: xb (bf16 cast) + out[:, :2048] concat copy
__launch_bounds__(256)
__global__ void xprep(const float* __restrict__ x, bf16* __restrict__ xb,
                      float* __restrict__ outp){
    const long idx = ((long)blockIdx.x*256 + threadIdx.x)*4;
    const float4 v = *(const float4*)&x[idx];
    B4 o; o.v[0]=f2b(v.x); o.v[1]=f2b(v.y); o.v[2]=f2b(v.z); o.v[3]=f2b(v.w);
    *reinterpret_cast<B4*>(&xb[idx]) = o;
    const long r = idx>>11, c = idx&2047;
    *(float4*)&outp[r*2560 + c] = v;
}

// LayerNorm over 2048-wide bf16 rows -> bf16.
__launch_bounds__(256)
__global__ void ln_rows(const bf16* __restrict__ inp, const float* __restrict__ gw,
                        const float* __restrict__ bw, bf16* __restrict__ outp){
    const long r = blockIdx.x;
    const int tid = threadIdx.x, k0 = tid*8;
    float v[8];
    const bf16* row = inp + r*2048;
    const B8 xv = *reinterpret_cast<const B8*>(&row[k0]);
    #pragma unroll
    for (int i=0;i<8;++i) v[i] = b2f(xv.v[i]);
    float s = 0.f, qq = 0.f;
    #pragma unroll
    for (int i=0;i<8;++i){ s += v[i]; qq += v[i]*v[i]; }
    #pragma unroll
    for (int o=32;o;o>>=1){ s += __shfl_xor(s,o); qq += __shfl_xor(qq,o); }
    __shared__ float s1[4], s2[4];
    if ((tid&63)==0){ s1[tid>>6]=s; s2[tid>>6]=qq; }
    __syncthreads();
    s  = s1[0]+s1[1]+s1[2]+s1[3];
    qq = s2[0]+s2[1]+s2[2]+s2[3];
    const float mean = s*(1.f/2048.f);
    const float var  = qq*(1.f/2048.f) - mean*mean;
    const float rinv = rsqrtf(var + 1e-5f);
    const float4 g1 = *(const float4*)&gw[k0];
    const float4 g2 = *(const float4*)&gw[k0+4];
    const float4 b1 = *(const float4*)&bw[k0];
    const float4 b2 = *(const float4*)&bw[k0+4];
    const float gg[8] = {g1.x,g1.y,g1.z,g1.w,g2.x,g2.y,g2.z,g2.w};
    const float bb[8] = {b1.x,b1.y,b1.z,b1.w,b2.x,b2.y,b2.z,b2.w};
    B8 o;
    #pragma unroll
    for (int i=0;i<8;++i) o.v[i] = f2b((v[i]-mean)*rinv*gg[i] + bb[i]);
    *reinterpret_cast<B8*>(&outp[r*2048 + k0]) = o;
}

extern "C" void kernel_launch(void* const* d_in, const int* in_sizes, int n_in,
                              void* d_out, int out_size, void* d_ws, size_t ws_size,
                              hipStream_t stream)
{
    (void)in_sizes; (void)n_in; (void)out_size;
    const float* x     = (const float*)d_in[0];
    const float* w_qkv = (const float*)d_in[1];
    const float* b_qkv = (const float*)d_in[2];
    const float* w_ao  = (const float*)d_in[3];
    const float* b_ao  = (const float*)d_in[4];
    const float* ln1g  = (const float*)d_in[5];
    const float* ln1b  = (const float*)d_in[6];
    const float* w_fc  = (const float*)d_in[7];
    const float* b_fc  = (const float*)d_in[8];
    const float* w_pr  = (const float*)d_in[9];
    const float* b_pr  = (const float*)d_in[10];
    const float* ln2g  = (const float*)d_in[11];
    const float* ln2b  = (const float*)d_in[12];
    const float* w_out = (const float*)d_in[13];
    const float* b_out = (const float*)d_in[14];
    float* out = (float*)d_out;
    char* ws = (char*)d_ws;

    const size_t NEEDED = 245366784ull;
    if (ws_size < NEEDED) return;

    bf16*  xb     = (bf16*)(ws);
    bf16*  qkv    = (bf16*)(ws + 33554432ull);
    bf16*  r1b    = (bf16*)(ws + 33554432ull);    // bf16 r1 (aliases dead qkv)
    bf16*  fcact  = (bf16*)(ws);
    float* kpart  = (float*)(ws);                 // phase 5: 4x[8192][512] f32 (67 MB)
    bf16*  vt     = (bf16*)(ws + 134217728ull);
    bf16*  Wfc_t  = (bf16*)(ws + 134217728ull);
    bf16*  rbufB  = (bf16*)(ws + 134217728ull);   // bf16 r2 [8192][2048]
    bf16*  Wpr_t  = (bf16*)(ws + 167772160ull);
    bf16*  Wqkv_t = (bf16*)(ws + 201326592ull);
    bf16*  nbuf   = (bf16*)(ws + 201326592ull);
    bf16*  Wao_t  = (bf16*)(ws + 234881024ull);
    bf16*  Wout_t = (bf16*)(ws + 243269632ull);

    const dim3 T(256);
    const int SMEM = 65536;
    const int SMEM_A = 163840;
    (void)hipFuncSetAttribute((const void*)gemm256<EPI_QKV>, hipFuncAttributeMaxDynamicSharedMemorySize, SMEM);
    (void)hipFuncSetAttribute((const void*)gemm256<EPI_AO>,  hipFuncAttributeMaxDynamicSharedMemorySize, SMEM);
    (void)hipFuncSetAttribute((const void*)gemm256<EPI_FC>,  hipFuncAttributeMaxDynamicSharedMemorySize, SMEM);
    (void)hipFuncSetAttribute((const void*)gemm256<EPI_PRB>, hipFuncAttributeMaxDynamicSharedMemorySize, SMEM);
    (void)hipFuncSetAttribute((const void*)gemm256<EPI_OUT>, hipFuncAttributeMaxDynamicSharedMemorySize, SMEM);
    (void)hipFuncSetAttribute((const void*)fattn,            hipFuncAttributeMaxDynamicSharedMemorySize, SMEM_A);

    // ---- phase 0: weight prep + x prep ----
    wtrans<<<dim3(192,64),T,0,stream>>>(w_qkv, Wqkv_t, 2048, 6144);
    wtrans<<<dim3(64,64), T,0,stream>>>(w_ao,  Wao_t,  2048, 2048);
    wtrans<<<dim3(16,64), T,0,stream>>>(w_out, Wout_t, 2048, 512);
    xprep<<<16384,T,0,stream>>>(x, xb, out);

    // ---- phase 1: qkv = x @ w_qkv + b_qkv; V-columns stored transposed into vt ----
    gemm256<EPI_QKV><<<dim3(768),dim3(512),SMEM,stream>>>(xb, Wqkv_t, qkv, b_qkv, vt,
        2048, 2048, 2048, 6144, 0, 24);

    // ---- phase 2: fused flash attention -> xb ----
    fattn<<<dim3(512),dim3(512),SMEM_A,stream>>>(qkv, vt, xb);

    // ---- phase 3: r1 = x + attn @ w_ao + b_ao (bf16), ln1 -> nbuf ----
    gemm256<EPI_AO><<<dim3(256),dim3(512),SMEM,stream>>>(xb, Wao_t, r1b, b_ao, x,
        2048, 2048, 2048, 2048, 2048, 8);
    ln_rows<<<8192,T,0,stream>>>(r1b, ln1g, ln1b, nbuf);

    // ---- phase 4: MLP ----
    wtrans<<<dim3(256,64),T,0,stream>>>(w_fc, Wfc_t, 2048, 8192);
    wtrans<<<dim3(64,256),T,0,stream>>>(w_pr, Wpr_t, 8192, 2048);
    gemm256<EPI_FC><<<dim3(1024),dim3(512),SMEM,stream>>>(nbuf, Wfc_t, fcact, b_fc, nullptr,
        2048, 2048, 2048, 8192, 0, 32);
    gemm256<EPI_PRB><<<dim3(256),dim3(512),SMEM,stream>>>(fcact, Wpr_t, rbufB, b_pr, nbuf,
        8192, 8192, 8192, 2048, 2048, 8);
    ln_rows<<<8192,T,0,stream>>>(rbufB, ln2g, ln2b, nbuf);

    // ---- phase 5: final head (split-K-4) + reduce ----
    gemm256<EPI_OUT><<<dim3(64,4),dim3(512),SMEM,stream>>>(nbuf, Wout_t, kpart, nullptr, nullptr,
        512, 2048, 2048, 512, 0, 2);
    kred<<<4096,T,0,stream>>>(kpart, b_out, out);
}

// Round 15
// 1071.791 us; speedup vs baseline: 7.9424x; 7.9424x over previous
//
#include <hip/hip_runtime.h>
#include <hip/hip_bf16.h>
#include <math.h>

using bf16 = __hip_bfloat16;
typedef __attribute__((ext_vector_type(8))) short s16x8;   // 8 bf16 = 4 VGPR
typedef __attribute__((ext_vector_type(4))) float f32x4;

struct __align__(16) B8 { bf16 v[8]; };
struct __align__(8)  B4 { bf16 v[4]; };

__device__ __forceinline__ float b2f(bf16 x){ return __bfloat162float(x); }
__device__ __forceinline__ bf16  f2b(float x){ return __float2bfloat16(x); }

enum { EPI_QKV=0, EPI_AO=3, EPI_FC=4, EPI_PRB=5, EPI_OUT=6 };

#define SCHED0 __builtin_amdgcn_sched_barrier(0)
#define PRIO1  __builtin_amdgcn_s_setprio(1)
#define PRIO0  __builtin_amdgcn_s_setprio(0)
#define BAR    __builtin_amdgcn_s_barrier()
#define VM4    asm volatile("s_waitcnt vmcnt(4)" ::: "memory")
#define VM2    asm volatile("s_waitcnt vmcnt(2)" ::: "memory")
#define VM0    asm volatile("s_waitcnt vmcnt(0)" ::: "memory")
#define LGKM0  asm volatile("s_waitcnt lgkmcnt(0)" ::: "memory")
#define AS1    const __attribute__((address_space(1))) void*
#define AS3    __attribute__((address_space(3))) void*

// ============================================================================
// R15 = R14's 64 KB-LDS 8-phase GEMM (schedule correctness-verified in R14)
// with __launch_bounds__(512, 2): allocator free to use 128 VGPR (R13-verified
// no-spill point); 64 KB LDS lets HW co-schedule 2 blocks/CU (m114 overlap).
// R14's (512,4) bound caused VGPR=64 + total spill (3.7 GB fetch) -- the bound
// was the bug, not the schedule.
// Requires M%256==0, N%256==0, K%64==0, NT>=2.
// ============================================================================
template<int EPI>
__launch_bounds__(512, 2)
__global__ void gemm256(const bf16* __restrict__ A, const bf16* __restrict__ B,
                        void* __restrict__ Cv, const float* __restrict__ bias,
                        const void* __restrict__ res,
                        int K, int lda, int ldb, int ldc, int ldres, int nbx)
{
    extern __shared__ __align__(16) bf16 lds[];
    bf16* Asl = lds;            // [2][128][64] = 32 KB
    bf16* Bsl = lds + 16384;    // [2][128][64] = 32 KB

    const int nwg = (int)gridDim.x;
    int wg = (int)blockIdx.x;
    if ((nwg & 7) == 0) wg = (wg & 7)*(nwg >> 3) + (wg >> 3);
    const int bx = wg % nbx, by = wg / nbx;
    const long m0 = (long)by*256, n0 = (long)bx*256;

    if constexpr (EPI==EPI_OUT){       // split-K: slice along K by blockIdx.y
        const long ko = (long)blockIdx.y * K;
        A += ko; B += ko;
        Cv = (void*)((float*)Cv + (long)blockIdx.y * 4194304);  // 8192*512
    }

    const int tid = threadIdx.x, wave = tid>>6, lane = tid&63;
    const int wr = wave>>2, wc = wave&3;          // 2 x 4 wave grid
    const int NT = K>>6;                          // K-tiles of 64 (>=2)
    const int fr = lane&15, fg = lane>>4;

    // fragment read bases; chunk swizzle ck = (kk*4+fg) ^ (fr&7) (thread-const)
    const int ck0 = fg ^ (fr&7);
    const int ck1 = (4+fg) ^ (fr&7);
    const bf16* aRd0 = Asl + wr*4096 + fr*64 + ck0*8;
    const bf16* aRd1 = Asl + wr*4096 + fr*64 + ck1*8;
    const bf16* bRd0 = Bsl + wc*2048 + fr*64 + ck0*8;
    const bf16* bRd1 = Bsl + wc*2048 + fr*64 + ck1*8;

    #define RDA(rh) { _Pragma("unroll") for (int i=0;i<4;++i){ \
        a[i][0] = *(const s16x8*)(aRd0 + (rh)*8192 + i*1024); \
        a[i][1] = *(const s16x8*)(aRd1 + (rh)*8192 + i*1024); } }
    #define RDB(dst, ch) { _Pragma("unroll") for (int j=0;j<2;++j){ \
        dst[j][0] = *(const s16x8*)(bRd0 + (ch)*8192 + j*1024); \
        dst[j][1] = *(const s16x8*)(bRd1 + (ch)*8192 + j*1024); } }

    // staging: half-tile = 128 rows x 64 k = 16 KB = 2 loads/thread.
    const int grow = tid>>3;
    const int gc0  = (tid&7) ^ (grow&7);
    const bf16* aP = A + (m0 + grow)*(long)lda + gc0*8;
    const bf16* bP = B + (n0 + grow)*(long)ldb + gc0*8;

    #define STGA(sh, koff) { _Pragma("unroll") for (int l=0;l<2;++l) \
        __builtin_amdgcn_global_load_lds((AS1)(aP + ((sh)*128 + l*64)*(long)lda + (koff)), \
            (AS3)(Asl + (sh)*8192 + l*4096 + wave*512 + lane*8), 16, 0, 0); }
    #define STGB(sh, koff) { _Pragma("unroll") for (int l=0;l<2;++l) \
        __builtin_amdgcn_global_load_lds((AS1)(bP + ((sh)*128 + l*64)*(long)ldb + (koff)), \
            (AS3)(Bsl + (sh)*8192 + l*4096 + wave*512 + lane*8), 16, 0, 0); }

    f32x4 acc[2][4][2][2];
    #pragma unroll
    for (int rh=0;rh<2;++rh)
        #pragma unroll
        for (int i=0;i<4;++i)
            #pragma unroll
            for (int ch=0;ch<2;++ch)
                #pragma unroll
                for (int j=0;j<2;++j)
                    #pragma unroll
                    for (int r=0;r<4;++r) acc[rh][i][ch][j][r] = 0.f;

    #define MM(rh, ch, BB) { PRIO1; \
        _Pragma("unroll") for (int i=0;i<4;++i) \
        _Pragma("unroll") for (int j=0;j<2;++j) \
        _Pragma("unroll") for (int kk=0;kk<2;++kk) \
            acc[rh][i][ch][j] = __builtin_amdgcn_mfma_f32_16x16x32_bf16(a[i][kk], BB[j][kk], acc[rh][i][ch][j], 0,0,0); \
        PRIO0; }

    s16x8 a[4][2], b0[2][2], b1[2][2];

    // ---- prologue: tile0 = Ah0,Bh0,Bh1,Ah1 (8 loads); retire Ah0,Bh0
    STGA(0,0); STGB(0,0); STGB(1,0); STGA(1,0);
    VM4; BAR;                // remaining in flight: [Bh1(0), Ah1(0)]

    for (int t=0; t<NT-1; ++t){
        // p1: reads Bh0,Ah0(t)
        RDB(b0,0); RDA(0);
        VM2;                          // retire Bh1(t)
        BAR; LGKM0; MM(0,0,b0); BAR;
        // p2: reads Bh1(t); stage Ah0(t+1)
        RDB(b1,1);
        STGA(0, 64);
        VM2;                          // retire Ah1(t)
        BAR; LGKM0; MM(0,1,b1); BAR;
        // p3: reads Ah1(t); stage Bh0,Bh1(t+1)
        RDA(1);
        STGB(0, 64); STGB(1, 64);
        BAR; LGKM0; MM(1,1,b1); BAR;
        // p4: stage Ah1(t+1); retire Ah0,Bh0(t+1)
        STGA(1, 64);
        VM4;
        BAR; LGKM0; MM(1,0,b0); BAR;
        aP += 64; bP += 64;
    }

    // ---- tail tile NT-1 (no stages)
    RDB(b0,0); RDA(0);
    VM2;                              // retire Bh1
    BAR; LGKM0; MM(0,0,b0); BAR;
    RDB(b1,1);
    VM0;                              // retire Ah1
    BAR; LGKM0; MM(0,1,b1); BAR;
    RDA(1);
    BAR; LGKM0; MM(1,1,b1); BAR;
    MM(1,0,b0);

    #undef RDA
    #undef RDB
    #undef STGA
    #undef STGB
    #undef MM

    // ---- epilogue: C row = m0+rh*128+wr*64+i*16+fg*4+r, col = n0+ch*128+wc*32+j*16+fr
    const bool vmode = (n0 >= 4096);          // used only by EPI_QKV (block-uniform)
    bf16* vtp = (bf16*)res;                   // EPI_QKV: vt base
    #pragma unroll
    for (int rh=0;rh<2;++rh)
        #pragma unroll
        for (int i=0;i<4;++i){
            const long mmb = m0 + rh*128 + wr*64 + i*16 + fg*4;
            #pragma unroll
            for (int ch=0;ch<2;++ch)
                #pragma unroll
                for (int j=0;j<2;++j){
                    const long nn = n0 + ch*128 + wc*32 + j*16 + fr;
                    if constexpr (EPI==EPI_QKV){
                        if (vmode){
                            B4 o;
                            #pragma unroll
                            for (int r=0;r<4;++r) o.v[r] = f2b(acc[rh][i][ch][j][r] + bias[nn]);
                            *reinterpret_cast<B4*>(vtp + (((mmb>>11)<<2) + ((nn-4096)>>9))*1048576
                                                   + (nn&511)*2048 + (mmb&2047)) = o;
                        } else {
                            #pragma unroll
                            for (int r=0;r<4;++r)
                                ((bf16*)Cv)[(mmb+r)*ldc + nn] = f2b(acc[rh][i][ch][j][r] + bias[nn]);
                        }
                    } else if constexpr (EPI==EPI_AO){
                        #pragma unroll
                        for (int r=0;r<4;++r)
                            ((bf16*)Cv)[(mmb+r)*ldc + nn] =
                                f2b(acc[rh][i][ch][j][r] + bias[nn] + ((const float*)res)[(mmb+r)*ldres + nn]);
                    } else if constexpr (EPI==EPI_PRB){
                        #pragma unroll
                        for (int r=0;r<4;++r)
                            ((bf16*)Cv)[(mmb+r)*ldc + nn] =
                                f2b(acc[rh][i][ch][j][r] + bias[nn] + b2f(((const bf16*)res)[(mmb+r)*ldres + nn]));
                    } else if constexpr (EPI==EPI_FC){
                        #pragma unroll
                        for (int r=0;r<4;++r){
                            const float tt = acc[rh][i][ch][j][r] + bias[nn];
                            const float g = 0.5f*tt*(1.f + tanhf(0.7978845608028654f*(tt + 0.044715f*tt*tt*tt)));
                            ((bf16*)Cv)[(mmb+r)*ldc + nn] = f2b(g);
                        }
                    } else { // EPI_OUT
                        #pragma unroll
                        for (int r=0;r<4;++r)
                            ((float*)Cv)[(mmb+r)*ldc + nn] = acc[rh][i][ch][j][r];  // bias in kred
                    }
                }
        }
}

// split-K reduce for OUT: out[r*2560+2048+c] = sum_4 partials + bias[c]
__launch_bounds__(256)
__global__ void kred(const float* __restrict__ p, const float* __restrict__ bias,
                     float* __restrict__ outp){
    const long idx = ((long)blockIdx.x*256 + threadIdx.x)*4;   // over 8192*512
    const long r = idx>>9, c = idx&511;
    float4 s0 = *(const float4*)&p[idx];
    const float4 s1 = *(const float4*)&p[idx + 4194304];
    const float4 s2 = *(const float4*)&p[idx + 8388608];
    const float4 s3 = *(const float4*)&p[idx + 12582912];
    const float4 bb = *(const float4*)&bias[c];
    s0.x += s1.x+s2.x+s3.x+bb.x; s0.y += s1.y+s2.y+s3.y+bb.y;
    s0.z += s1.z+s2.z+s3.z+bb.z; s0.w += s1.w+s2.w+s3.w+bb.w;
    *(float4*)&outp[r*2560 + 2048 + c] = s0;
}

// ============================================================================
// Fused causal flash-attention (R9-verified, untouched).
// ============================================================================
__launch_bounds__(512, 2)
__global__ void fattn(const bf16* __restrict__ qkv, const bf16* __restrict__ vt,
                      bf16* __restrict__ outp)
{
    extern __shared__ __align__(16) bf16 sh[];
    bf16* sQ = sh;                    // [64][512] swz(row&7)      64 KB
    bf16* sK = sh + 32768;            // 3 slots [128][64] swz     48 KB
    bf16* sP = sh + 57344;            // [64][128] swz(rl&15)      16 KB
    bf16* sV = sh + 65536;            // 2 bufs [256][32] swz      32 KB
    float* part = (float*)(sh + 32768);   // alias sK (dead at epilogue)

    const int bid = blockIdx.x;
    const int xcd = bid&7, t5 = bid>>3, rnd = t5>>5, ci = t5&31;
    const int bh = xcd*2 + rnd, b = bh>>2, h = bh&3;
    const int ib = 31 - ci;
    const int njb = (ib>>1) + 1;
    const int tid = threadIdx.x, wave = tid>>6, lane = tid&63;
    const int wr = wave>>2, wc = wave&3;
    const int fr = lane&15, fg = lane>>4;

    const bf16* Qg = qkv + ((long)b*2048 + ib*64)*6144 + h*512;
    const bf16* Kg = qkv + (long)b*2048*6144 + 2048 + h*512;
    const bf16* Vtb = vt + (long)bh*1048576;
    const float SCALE = 0.044194173824159216f;

    #define STGQ { _Pragma("unroll") for (int l=0;l<8;++l){                          \
        const int row = l*8 + (tid>>6);                                              \
        const int c   = (tid&63) ^ (row&7);                                          \
        __builtin_amdgcn_global_load_lds((AS1)(Qg + (long)row*6144 + c*8),           \
            (AS3)(sQ + l*4096 + wave*512 + lane*8), 16,0,0); } }
    #define STGK(slot, ec, KJ) { _Pragma("unroll") for (int l=0;l<2;++l){            \
        const int row = l*64 + (tid>>3);                                             \
        const int c   = (tid&7) ^ (row&7);                                           \
        __builtin_amdgcn_global_load_lds((AS1)((KJ) + (long)row*6144 + (ec)*64 + c*8),\
            (AS3)(sK + (slot)*8192 + l*4096 + wave*512 + lane*8), 16,0,0); } }
    #define STGV(buf, kf, eh, VJ) { _Pragma("unroll") for (int l=0;l<2;++l){         \
        const int row = l*128 + (tid>>2);                                            \
        const int c   = (tid&3) ^ ((row + (row>>2))&3);                              \
        __builtin_amdgcn_global_load_lds((AS1)((VJ) + (long)((eh)*256+row)*2048 + (kf)*32 + c*8),\
            (AS3)(sV + (buf)*8192 + l*4096 + wave*512 + lane*8), 16,0,0); } }

    f32x4 acc[2][8];
    #pragma unroll
    for (int m=0;m<2;++m)
        #pragma unroll
        for (int j=0;j<8;++j)
            #pragma unroll
            for (int r=0;r<4;++r) acc[m][j][r] = 0.f;
    float l_l[2][4];
    #pragma unroll
    for (int m=0;m<2;++m){ l_l[m][0]=0.f; l_l[m][1]=0.f; l_l[m][2]=0.f; l_l[m][3]=0.f; }

    const bf16* KgJ = Kg;
    const bf16* VtJ = Vtb;

    STGQ;
    STGK(0, 0, KgJ);
    STGK(1, 1, KgJ);
    VM2; SCHED0; BAR;

    for (int jb=0; jb<njb; ++jb){
        const bool last = (jb == njb-1);
        f32x4 sacc[2][2];
        #pragma unroll
        for (int m=0;m<2;++m)
            #pragma unroll
            for (int nf=0;nf<2;++nf)
                #pragma unroll
                for (int r=0;r<4;++r) sacc[m][nf][r] = 0.f;

        #pragma unroll
        for (int ec=0; ec<8; ++ec){
            const int slot = ec%3;
            s16x8 qa[2][2], kb[2][2];
            #pragma unroll
            for (int m=0;m<2;++m)
                #pragma unroll
                for (int kk=0;kk<2;++kk){
                    const int row = wr*32 + m*16 + fr;
                    const int c = (ec*2+kk)*4 + fg;
                    qa[m][kk] = *(const s16x8*)(sQ + row*512 + ((c ^ (row&7))*8));
                }
            #pragma unroll
            for (int nf=0;nf<2;++nf)
                #pragma unroll
                for (int kk=0;kk<2;++kk){
                    const int row = wc*32 + nf*16 + fr;
                    const int c = kk*4 + fg;
                    kb[nf][kk] = *(const s16x8*)(sK + slot*8192 + row*64 + ((c ^ (row&7))*8));
                }
            if (ec < 6) STGK((ec+2)%3, ec+2, KgJ);
            PRIO1;
            #pragma unroll
            for (int m=0;m<2;++m)
                #pragma unroll
                for (int nf=0;nf<2;++nf)
                    #pragma unroll
                    for (int kk=0;kk<2;++kk)
                        sacc[m][nf] = __builtin_amdgcn_mfma_f32_16x16x32_bf16(qa[m][kk], kb[nf][kk], sacc[m][nf], 0,0,0);
            PRIO0;
            if (ec < 6) { VM2; } else if (ec == 6) { VM0; }
            SCHED0; BAR;
        }

        const int doff = (njb-1)*128 - ib*64;
        #pragma unroll
        for (int m=0;m<2;++m)
            #pragma unroll
            for (int nf=0;nf<2;++nf)
                #pragma unroll
                for (int r=0;r<4;++r){
                    float pv = __expf(sacc[m][nf][r]*SCALE - 4.0f);
                    const int rl = wr*32 + m*16 + fg*4 + r;
                    const int cl = wc*32 + nf*16 + fr;
                    if (last && (cl + doff > rl)) pv = 0.f;
                    sP[rl*128 + (((cl>>3) ^ (rl&15))*8) + (cl&7)] = f2b(pv);
                    l_l[m][r] += pv;
                }
        STGV(0, 0, 0, VtJ);
        if (!last){ STGK(0, 0, KgJ + 786432); STGK(1, 1, KgJ + 786432); }
        if (!last){ VM4; } else { VM0; }
        LGKM0; SCHED0; BAR;

        s16x8 pa[2];
        #pragma unroll
        for (int v=0; v<8; ++v){
            const int kf = v>>1, eh = v&1, buf = v&1;
            if (eh == 0){
                #pragma unroll
                for (int m=0;m<2;++m){
                    const int row = wr*32 + m*16 + fr;
                    const int c = kf*4 + fg;
                    pa[m] = *(const s16x8*)(sP + row*128 + ((c ^ (row&15))*8));
                }
            }
            s16x8 vb[4];
            #pragma unroll
            for (int nf=0;nf<4;++nf){
                const int row = wc*64 + nf*16 + fr;
                vb[nf] = *(const s16x8*)(sV + buf*8192 + row*32 + (((fg ^ ((row + (row>>2))&3)))*8));
            }
            if (v < 7) STGV((v+1)&1, (v+1)>>1, (v+1)&1, VtJ);
            PRIO1;
            #pragma unroll
            for (int m=0;m<2;++m)
                #pragma unroll
                for (int nf=0;nf<4;++nf)
                    acc[m][eh*4+nf] = __builtin_amdgcn_mfma_f32_16x16x32_bf16(pa[m], vb[nf], acc[m][eh*4+nf], 0,0,0);
            PRIO0;
            if (v < 7) { VM0; }
            SCHED0; BAR;
        }
        KgJ += 786432;
        VtJ += 128;
    }

    #pragma unroll
    for (int m=0;m<2;++m)
        #pragma unroll
        for (int r=0;r<4;++r){
            float v = l_l[m][r];
            v += __shfl_xor(v, 1); v += __shfl_xor(v, 2);
            v += __shfl_xor(v, 4); v += __shfl_xor(v, 8);
            l_l[m][r] = v;
        }
    if (fr == 0){
        #pragma unroll
        for (int m=0;m<2;++m)
            #pragma unroll
            for (int r=0;r<4;++r)
                part[(wr*32 + m*16 + fg*4 + r)*4 + wc] = l_l[m][r];
    }
    LGKM0; SCHED0; BAR;

    bf16* orow = outp + ((long)b*2048 + ib*64)*2048 + h*512;
    #pragma unroll
    for (int m=0;m<2;++m)
        #pragma unroll
        for (int r=0;r<4;++r){
            const int rl = wr*32 + m*16 + fg*4 + r;
            const f32x4 pp = *(const f32x4*)(part + rl*4);
            const float rinv = 1.f/(pp[0]+pp[1]+pp[2]+pp[3]);
            #pragma unroll
            for (int j=0;j<8;++j){
                const int e = (j>>2)*256 + wc*64 + (j&3)*16 + fr;
                orow[(long)rl*2048 + e] = f2b(acc[m][j][r]*rinv);
            }
        }
    #undef STGQ
    #undef STGK
    #undef STGV
}

// fp32 [Kd,Nd] -> bf16 [Nd,Kd]
__launch_bounds__(256)
__global__ void wtrans(const float* __restrict__ W, bf16* __restrict__ Wt, int Kd, int Nd){
    __shared__ float t[32][33];
    const int n0 = blockIdx.x*32, k0 = blockIdx.y*32;
    const int tx = threadIdx.x&31, ty = threadIdx.x>>5;
    #pragma unroll
    for (int i=0;i<32;i+=8) t[ty+i][tx] = W[(long)(k0+ty+i)*Nd + n0+tx];
    __syncthreads();
    #pragma unroll
    for (int i=0;i<32;i+=8) Wt[(long)(n0+ty+i)*Kd + k0+tx] = f2b(t[tx][ty+i]);
}

// x read ONCE: xb (bf16 cast) + out[:, :2048] concat copy
__launch_bounds__(256)
__global__ void xprep(const float* __restrict__ x, bf16* __restrict__ xb,
                      float* __restrict__ outp){
    const long idx = ((long)blockIdx.x*256 + threadIdx.x)*4;
    const float4 v = *(const float4*)&x[idx];
    B4 o; o.v[0]=f2b(v.x); o.v[1]=f2b(v.y); o.v[2]=f2b(v.z); o.v[3]=f2b(v.w);
    *reinterpret_cast<B4*>(&xb[idx]) = o;
    const long r = idx>>11, c = idx&2047;
    *(float4*)&outp[r*2560 + c] = v;
}

// LayerNorm over 2048-wide bf16 rows -> bf16.
__launch_bounds__(256)
__global__ void ln_rows(const bf16* __restrict__ inp, const float* __restrict__ gw,
                        const float* __restrict__ bw, bf16* __restrict__ outp){
    const long r = blockIdx.x;
    const int tid = threadIdx.x, k0 = tid*8;
    float v[8];
    const bf16* row = inp + r*2048;
    const B8 xv = *reinterpret_cast<const B8*>(&row[k0]);
    #pragma unroll
    for (int i=0;i<8;++i) v[i] = b2f(xv.v[i]);
    float s = 0.f, qq = 0.f;
    #pragma unroll
    for (int i=0;i<8;++i){ s += v[i]; qq += v[i]*v[i]; }
    #pragma unroll
    for (int o=32;o;o>>=1){ s += __shfl_xor(s,o); qq += __shfl_xor(qq,o); }
    __shared__ float s1[4], s2[4];
    if ((tid&63)==0){ s1[tid>>6]=s; s2[tid>>6]=qq; }
    __syncthreads();
    s  = s1[0]+s1[1]+s1[2]+s1[3];
    qq = s2[0]+s2[1]+s2[2]+s2[3];
    const float mean = s*(1.f/2048.f);
    const float var  = qq*(1.f/2048.f) - mean*mean;
    const float rinv = rsqrtf(var + 1e-5f);
    const float4 g1 = *(const float4*)&gw[k0];
    const float4 g2 = *(const float4*)&gw[k0+4];
    const float4 b1 = *(const float4*)&bw[k0];
    const float4 b2 = *(const float4*)&bw[k0+4];
    const float gg[8] = {g1.x,g1.y,g1.z,g1.w,g2.x,g2.y,g2.z,g2.w};
    const float bb[8] = {b1.x,b1.y,b1.z,b1.w,b2.x,b2.y,b2.z,b2.w};
    B8 o;
    #pragma unroll
    for (int i=0;i<8;++i) o.v[i] = f2b((v[i]-mean)*rinv*gg[i] + bb[i]);
    *reinterpret_cast<B8*>(&outp[r*2048 + k0]) = o;
}

extern "C" void kernel_launch(void* const* d_in, const int* in_sizes, int n_in,
                              void* d_out, int out_size, void* d_ws, size_t ws_size,
                              hipStream_t stream)
{
    (void)in_sizes; (void)n_in; (void)out_size;
    const float* x     = (const float*)d_in[0];
    const float* w_qkv = (const float*)d_in[1];
    const float* b_qkv = (const float*)d_in[2];
    const float* w_ao  = (const float*)d_in[3];
    const float* b_ao  = (const float*)d_in[4];
    const float* ln1g  = (const float*)d_in[5];
    const float* ln1b  = (const float*)d_in[6];
    const float* w_fc  = (const float*)d_in[7];
    const float* b_fc  = (const float*)d_in[8];
    const float* w_pr  = (const float*)d_in[9];
    const float* b_pr  = (const float*)d_in[10];
    const float* ln2g  = (const float*)d_in[11];
    const float* ln2b  = (const float*)d_in[12];
    const float* w_out = (const float*)d_in[13];
    const float* b_out = (const float*)d_in[14];
    float* out = (float*)d_out;
    char* ws = (char*)d_ws;

    const size_t NEEDED = 245366784ull;
    if (ws_size < NEEDED) return;

    bf16*  xb     = (bf16*)(ws);
    bf16*  qkv    = (bf16*)(ws + 33554432ull);
    bf16*  r1b    = (bf16*)(ws + 33554432ull);    // bf16 r1 (aliases dead qkv)
    bf16*  fcact  = (bf16*)(ws);
    float* kpart  = (float*)(ws);                 // phase 5: 4x[8192][512] f32 (67 MB)
    bf16*  vt     = (bf16*)(ws + 134217728ull);
    bf16*  Wfc_t  = (bf16*)(ws + 134217728ull);
    bf16*  rbufB  = (bf16*)(ws + 134217728ull);   // bf16 r2 [8192][2048]
    bf16*  Wpr_t  = (bf16*)(ws + 167772160ull);
    bf16*  Wqkv_t = (bf16*)(ws + 201326592ull);
    bf16*  nbuf   = (bf16*)(ws + 201326592ull);
    bf16*  Wao_t  = (bf16*)(ws + 234881024ull);
    bf16*  Wout_t = (bf16*)(ws + 243269632ull);

    const dim3 T(256);
    const int SMEM = 65536;
    const int SMEM_A = 163840;
    (void)hipFuncSetAttribute((const void*)gemm256<EPI_QKV>, hipFuncAttributeMaxDynamicSharedMemorySize, SMEM);
    (void)hipFuncSetAttribute((const void*)gemm256<EPI_AO>,  hipFuncAttributeMaxDynamicSharedMemorySize, SMEM);
    (void)hipFuncSetAttribute((const void*)gemm256<EPI_FC>,  hipFuncAttributeMaxDynamicSharedMemorySize, SMEM);
    (void)hipFuncSetAttribute((const void*)gemm256<EPI_PRB>, hipFuncAttributeMaxDynamicSharedMemorySize, SMEM);
    (void)hipFuncSetAttribute((const void*)gemm256<EPI_OUT>, hipFuncAttributeMaxDynamicSharedMemorySize, SMEM);
    (void)hipFuncSetAttribute((const void*)fattn,            hipFuncAttributeMaxDynamicSharedMemorySize, SMEM_A);

    // ---- phase 0: weight prep + x prep ----
    wtrans<<<dim3(192,64),T,0,stream>>>(w_qkv, Wqkv_t, 2048, 6144);
    wtrans<<<dim3(64,64), T,0,stream>>>(w_ao,  Wao_t,  2048, 2048);
    wtrans<<<dim3(16,64), T,0,stream>>>(w_out, Wout_t, 2048, 512);
    xprep<<<16384,T,0,stream>>>(x, xb, out);

    // ---- phase 1: qkv = x @ w_qkv + b_qkv; V-columns stored transposed into vt ----
    gemm256<EPI_QKV><<<dim3(768),dim3(512),SMEM,stream>>>(xb, Wqkv_t, qkv, b_qkv, vt,
        2048, 2048, 2048, 6144, 0, 24);

    // ---- phase 2: fused flash attention -> xb ----
    fattn<<<dim3(512),dim3(512),SMEM_A,stream>>>(qkv, vt, xb);

    // ---- phase 3: r1 = x + attn @ w_ao + b_ao (bf16), ln1 -> nbuf ----
    gemm256<EPI_AO><<<dim3(256),dim3(512),SMEM,stream>>>(xb, Wao_t, r1b, b_ao, x,
        2048, 2048, 2048, 2048, 2048, 8);
    ln_rows<<<8192,T,0,stream>>>(r1b, ln1g, ln1b, nbuf);

    // ---- phase 4: MLP ----
    wtrans<<<dim3(256,64),T,0,stream>>>(w_fc, Wfc_t, 2048, 8192);
    wtrans<<<dim3(64,256),T,0,stream>>>(w_pr, Wpr_t, 8192, 2048);
    gemm256<EPI_FC><<<dim3(1024),dim3(512),SMEM,stream>>>(nbuf, Wfc_t, fcact, b_fc, nullptr,
        2048, 2048, 2048, 8192, 0, 32);
    gemm256<EPI_PRB><<<dim3(256),dim3(512),SMEM,stream>>>(fcact, Wpr_t, rbufB, b_pr, nbuf,
        8192, 8192, 8192, 2048, 2048, 8);
    ln_rows<<<8192,T,0,stream>>>(rbufB, ln2g, ln2b, nbuf);

    // ---- phase 5: final head (split-K-4) + reduce ----
    gemm256<EPI_OUT><<<dim3(64,4),dim3(512),SMEM,stream>>>(nbuf, Wout_t, kpart, nullptr, nullptr,
        512, 2048, 2048, 512, 0, 2);
    kred<<<4096,T,0,stream>>>(kpart, b_out, out);
}

// Round 16
// 1041.841 us; speedup vs baseline: 8.1708x; 1.0287x over previous
//
#include <hip/hip_runtime.h>
#include <hip/hip_bf16.h>
#include <math.h>

using bf16 = __hip_bfloat16;
typedef __attribute__((ext_vector_type(8))) short s16x8;   // 8 bf16 = 4 VGPR
typedef __attribute__((ext_vector_type(4))) float f32x4;

struct __align__(16) B8 { bf16 v[8]; };
struct __align__(8)  B4 { bf16 v[4]; };

__device__ __forceinline__ float b2f(bf16 x){ return __bfloat162float(x); }
__device__ __forceinline__ bf16  f2b(float x){ return __float2bfloat16(x); }

enum { EPI_QKV=0, EPI_AO=3, EPI_FC=4, EPI_PRB=5, EPI_OUT=6 };

#define SCHED0 __builtin_amdgcn_sched_barrier(0)
#define PRIO1  __builtin_amdgcn_s_setprio(1)
#define PRIO0  __builtin_amdgcn_s_setprio(0)
#define BAR    __builtin_amdgcn_s_barrier()
#define VM6    asm volatile("s_waitcnt vmcnt(6)" ::: "memory")
#define VM4    asm volatile("s_waitcnt vmcnt(4)" ::: "memory")
#define VM2    asm volatile("s_waitcnt vmcnt(2)" ::: "memory")
#define VM0    asm volatile("s_waitcnt vmcnt(0)" ::: "memory")
#define LGKM0  asm volatile("s_waitcnt lgkmcnt(0)" ::: "memory")
#define AS1    const __attribute__((address_space(1))) void*
#define AS3    __attribute__((address_space(3))) void*

// ============================================================================
// FINAL (== R13, best verified 1050 us): 8-phase GEMM, 128 KB dbuf LDS,
// counted vmcnt(6)/tile, XOR-swizzled LDS (0 bank conflicts), setprio, XCD
// swizzle.  EPI_QKV: V-region blocks (n0>=4096) store transposed into vt.
// EPI_AO: bf16 out.  EPI_OUT: split-K via blockIdx.y, bias in kred.
// Plain-HIP plateau: 39% MfmaUtil across 7 structural variants.
// Requires M%256==0, N%256==0, K%128==0, K>=256.
// ============================================================================
template<int EPI>
__launch_bounds__(512, 2)
__global__ void gemm256(const bf16* __restrict__ A, const bf16* __restrict__ B,
                        void* __restrict__ Cv, const float* __restrict__ bias,
                        const void* __restrict__ res,
                        int K, int lda, int ldb, int ldc, int ldres, int nbx)
{
    extern __shared__ __align__(16) bf16 lds[];
    bf16* Asl = lds;            // [2][2][128][64]
    bf16* Bsl = lds + 32768;

    const int nwg = (int)gridDim.x;
    int wg = (int)blockIdx.x;
    if ((nwg & 7) == 0) wg = (wg & 7)*(nwg >> 3) + (wg >> 3);
    const int bx = wg % nbx, by = wg / nbx;
    const long m0 = (long)by*256, n0 = (long)bx*256;

    if constexpr (EPI==EPI_OUT){       // split-K: slice along K by blockIdx.y
        const long ko = (long)blockIdx.y * K;
        A += ko; B += ko;
        Cv = (void*)((float*)Cv + (long)blockIdx.y * 4194304);  // 8192*512
    }

    const int tid = threadIdx.x, wave = tid>>6, lane = tid&63;
    const int wr = wave>>2, wc = wave&3;          // 2 x 4 wave grid
    const int NT = K>>6;                          // K-tiles of 64 (even, >=4)
    const int fr = lane&15, fg = lane>>4;

    // fragment read bases; chunk swizzle ck = (kk*4+fg) ^ (fr&7) (thread-const)
    const int ck0 = fg ^ (fr&7);
    const int ck1 = (4+fg) ^ (fr&7);
    const bf16* aRd0 = Asl + wr*4096 + fr*64 + ck0*8;
    const bf16* aRd1 = Asl + wr*4096 + fr*64 + ck1*8;
    const bf16* bRd0 = Bsl + wc*2048 + fr*64 + ck0*8;
    const bf16* bRd1 = Bsl + wc*2048 + fr*64 + ck1*8;

    #define RDA(d, rh) { _Pragma("unroll") for (int i=0;i<4;++i){ \
        a[i][0] = *(const s16x8*)(aRd0 + (d)*16384 + (rh)*8192 + i*1024); \
        a[i][1] = *(const s16x8*)(aRd1 + (d)*16384 + (rh)*8192 + i*1024); } }
    #define RDB(dst, d, ch) { _Pragma("unroll") for (int j=0;j<2;++j){ \
        dst[j][0] = *(const s16x8*)(bRd0 + (d)*16384 + (ch)*8192 + j*1024); \
        dst[j][1] = *(const s16x8*)(bRd1 + (d)*16384 + (ch)*8192 + j*1024); } }

    // staging: half-tile = 128 rows x 64 k = 16 KB = 2 loads/thread.
    const int grow = tid>>3;
    const int gc0  = (tid&7) ^ (grow&7);
    const bf16* aP = A + (m0 + grow)*(long)lda + gc0*8;
    const bf16* bP = B + (n0 + grow)*(long)ldb + gc0*8;

    #define STGA(sd, sh, koff) { _Pragma("unroll") for (int l=0;l<2;++l) \
        __builtin_amdgcn_global_load_lds((AS1)(aP + ((sh)*128 + l*64)*(long)lda + (koff)), \
            (AS3)(Asl + (sd)*16384 + (sh)*8192 + l*4096 + wave*512 + lane*8), 16, 0, 0); }
    #define STGB(sd, sh, koff) { _Pragma("unroll") for (int l=0;l<2;++l) \
        __builtin_amdgcn_global_load_lds((AS1)(bP + ((sh)*128 + l*64)*(long)ldb + (koff)), \
            (AS3)(Bsl + (sd)*16384 + (sh)*8192 + l*4096 + wave*512 + lane*8), 16, 0, 0); }

    f32x4 acc[2][4][2][2];
    #pragma unroll
    for (int rh=0;rh<2;++rh)
        #pragma unroll
        for (int i=0;i<4;++i)
            #pragma unroll
            for (int ch=0;ch<2;++ch)
                #pragma unroll
                for (int j=0;j<2;++j)
                    #pragma unroll
                    for (int r=0;r<4;++r) acc[rh][i][ch][j][r] = 0.f;

    #define MM(rh, ch, BB) { PRIO1; \
        _Pragma("unroll") for (int i=0;i<4;++i) \
        _Pragma("unroll") for (int j=0;j<2;++j) \
        _Pragma("unroll") for (int kk=0;kk<2;++kk) \
            acc[rh][i][ch][j] = __builtin_amdgcn_mfma_f32_16x16x32_bf16(a[i][kk], BB[j][kk], acc[rh][i][ch][j], 0,0,0); \
        PRIO0; }

    s16x8 a[4][2], b0[2][2], b1[2][2];

    // ---- prologue: tile0 (4 halves) then tile1 {Ah0,Bh1,Ah1}
    STGA(0,0,0);  STGB(0,1,0);  STGA(0,1,0);  STGB(0,0,0);
    STGA(1,0,64); STGB(1,1,64); STGA(1,1,64);
    VM6; BAR;                // retire tile0 fully; 6 in flight

    for (int t=0; t<=NT-4; t+=2){
        // ======== tile t (dbuf0) ========
        RDB(b0,0,0); RDA(0,0); STGB(1,0,64);
        BAR; LGKM0; MM(0,0,b0); BAR;
        RDB(b1,0,1);           STGA(0,0,128);
        BAR; LGKM0; MM(0,1,b1); BAR;
        RDA(0,1);              STGB(0,1,128);
        BAR; LGKM0; MM(1,1,b1); BAR;
                               STGA(0,1,128); VM6;
        BAR; LGKM0; MM(1,0,b0); BAR;
        // ======== tile t+1 (dbuf1) ========
        RDB(b0,1,0); RDA(1,0); STGB(0,0,128);
        BAR; LGKM0; MM(0,0,b0); BAR;
        RDB(b1,1,1);           STGA(1,0,192);
        BAR; LGKM0; MM(0,1,b1); BAR;
        RDA(1,1);              STGB(1,1,192);
        BAR; LGKM0; MM(1,1,b1); BAR;
                               STGA(1,1,192); VM6;
        BAR; LGKM0; MM(1,0,b0); BAR;
        aP += 128; bP += 128;
    }

    // ======== tail: tile NT-2 (dbuf0) ========
    RDB(b0,0,0); RDA(0,0); STGB(1,0,64);
    BAR; LGKM0; MM(0,0,b0); BAR;
    RDB(b1,0,1);
    BAR; LGKM0; MM(0,1,b1); BAR;
    RDA(0,1);
    BAR; LGKM0; MM(1,1,b1); BAR;
    VM0;
    BAR; LGKM0; MM(1,0,b0); BAR;
    // ======== tail: tile NT-1 (dbuf1) ========
    RDB(b0,1,0); RDA(1,0);
    BAR; LGKM0; MM(0,0,b0); BAR;
    RDB(b1,1,1);
    BAR; LGKM0; MM(0,1,b1); BAR;
    RDA(1,1);
    BAR; LGKM0; MM(1,1,b1); BAR;
    MM(1,0,b0);

    #undef RDA
    #undef RDB
    #undef STGA
    #undef STGB
    #undef MM

    // ---- epilogue: C row = m0+rh*128+wr*64+i*16+fg*4+r, col = n0+ch*128+wc*32+j*16+fr
    const bool vmode = (n0 >= 4096);          // used only by EPI_QKV (block-uniform)
    bf16* vtp = (bf16*)res;                   // EPI_QKV: vt base
    #pragma unroll
    for (int rh=0;rh<2;++rh)
        #pragma unroll
        for (int i=0;i<4;++i){
            const long mmb = m0 + rh*128 + wr*64 + i*16 + fg*4;
            #pragma unroll
            for (int ch=0;ch<2;++ch)
                #pragma unroll
                for (int j=0;j<2;++j){
                    const long nn = n0 + ch*128 + wc*32 + j*16 + fr;
                    if constexpr (EPI==EPI_QKV){
                        if (vmode){
                            // V: transposed store into vt[bh][e][s], 4 consecutive s packed
                            B4 o;
                            #pragma unroll
                            for (int r=0;r<4;++r) o.v[r] = f2b(acc[rh][i][ch][j][r] + bias[nn]);
                            *reinterpret_cast<B4*>(vtp + (((mmb>>11)<<2) + ((nn-4096)>>9))*1048576
                                                   + (nn&511)*2048 + (mmb&2047)) = o;
                        } else {
                            #pragma unroll
                            for (int r=0;r<4;++r)
                                ((bf16*)Cv)[(mmb+r)*ldc + nn] = f2b(acc[rh][i][ch][j][r] + bias[nn]);
                        }
                    } else if constexpr (EPI==EPI_AO){
                        #pragma unroll
                        for (int r=0;r<4;++r)
                            ((bf16*)Cv)[(mmb+r)*ldc + nn] =
                                f2b(acc[rh][i][ch][j][r] + bias[nn] + ((const float*)res)[(mmb+r)*ldres + nn]);
                    } else if constexpr (EPI==EPI_PRB){
                        #pragma unroll
                        for (int r=0;r<4;++r)
                            ((bf16*)Cv)[(mmb+r)*ldc + nn] =
                                f2b(acc[rh][i][ch][j][r] + bias[nn] + b2f(((const bf16*)res)[(mmb+r)*ldres + nn]));
                    } else if constexpr (EPI==EPI_FC){
                        #pragma unroll
                        for (int r=0;r<4;++r){
                            const float tt = acc[rh][i][ch][j][r] + bias[nn];
                            const float g = 0.5f*tt*(1.f + tanhf(0.7978845608028654f*(tt + 0.044715f*tt*tt*tt)));
                            ((bf16*)Cv)[(mmb+r)*ldc + nn] = f2b(g);
                        }
                    } else { // EPI_OUT
                        #pragma unroll
                        for (int r=0;r<4;++r)
                            ((float*)Cv)[(mmb+r)*ldc + nn] = acc[rh][i][ch][j][r];  // bias in kred
                    }
                }
        }
}

// split-K reduce for OUT: out[r*2560+2048+c] = sum_4 partials + bias[c]
__launch_bounds__(256)
__global__ void kred(const float* __restrict__ p, const float* __restrict__ bias,
                     float* __restrict__ outp){
    const long idx = ((long)blockIdx.x*256 + threadIdx.x)*4;   // over 8192*512
    const long r = idx>>9, c = idx&511;
    float4 s0 = *(const float4*)&p[idx];
    const float4 s1 = *(const float4*)&p[idx + 4194304];
    const float4 s2 = *(const float4*)&p[idx + 8388608];
    const float4 s3 = *(const float4*)&p[idx + 12582912];
    const float4 bb = *(const float4*)&bias[c];
    s0.x += s1.x+s2.x+s3.x+bb.x; s0.y += s1.y+s2.y+s3.y+bb.y;
    s0.z += s1.z+s2.z+s3.z+bb.z; s0.w += s1.w+s2.w+s3.w+bb.w;
    *(float4*)&outp[r*2560 + 2048 + c] = s0;
}

// ============================================================================
// Fused causal flash-attention (R9-verified).  Grid 512, 8 waves, QBLK=64,
// Q resident; K ring-3, V ring-2, counted vmcnt; fixed-shift softmax.
// ============================================================================
__launch_bounds__(512, 2)
__global__ void fattn(const bf16* __restrict__ qkv, const bf16* __restrict__ vt,
                      bf16* __restrict__ outp)
{
    extern __shared__ __align__(16) bf16 sh[];
    bf16* sQ = sh;                    // [64][512] swz(row&7)      64 KB
    bf16* sK = sh + 32768;            // 3 slots [128][64] swz     48 KB
    bf16* sP = sh + 57344;            // [64][128] swz(rl&15)      16 KB
    bf16* sV = sh + 65536;            // 2 bufs [256][32] swz      32 KB
    float* part = (float*)(sh + 32768);   // alias sK (dead at epilogue)

    const int bid = blockIdx.x;
    const int xcd = bid&7, t5 = bid>>3, rnd = t5>>5, ci = t5&31;
    const int bh = xcd*2 + rnd, b = bh>>2, h = bh&3;
    const int ib = 31 - ci;
    const int njb = (ib>>1) + 1;
    const int tid = threadIdx.x, wave = tid>>6, lane = tid&63;
    const int wr = wave>>2, wc = wave&3;
    const int fr = lane&15, fg = lane>>4;

    const bf16* Qg = qkv + ((long)b*2048 + ib*64)*6144 + h*512;
    const bf16* Kg = qkv + (long)b*2048*6144 + 2048 + h*512;
    const bf16* Vtb = vt + (long)bh*1048576;
    const float SCALE = 0.044194173824159216f;

    #define STGQ { _Pragma("unroll") for (int l=0;l<8;++l){                          \
        const int row = l*8 + (tid>>6);                                              \
        const int c   = (tid&63) ^ (row&7);                                          \
        __builtin_amdgcn_global_load_lds((AS1)(Qg + (long)row*6144 + c*8),           \
            (AS3)(sQ + l*4096 + wave*512 + lane*8), 16,0,0); } }
    #define STGK(slot, ec, KJ) { _Pragma("unroll") for (int l=0;l<2;++l){            \
        const int row = l*64 + (tid>>3);                                             \
        const int c   = (tid&7) ^ (row&7);                                           \
        __builtin_amdgcn_global_load_lds((AS1)((KJ) + (long)row*6144 + (ec)*64 + c*8),\
            (AS3)(sK + (slot)*8192 + l*4096 + wave*512 + lane*8), 16,0,0); } }
    #define STGV(buf, kf, eh, VJ) { _Pragma("unroll") for (int l=0;l<2;++l){         \
        const int row = l*128 + (tid>>2);                                            \
        const int c   = (tid&3) ^ ((row + (row>>2))&3);                              \
        __builtin_amdgcn_global_load_lds((AS1)((VJ) + (long)((eh)*256+row)*2048 + (kf)*32 + c*8),\
            (AS3)(sV + (buf)*8192 + l*4096 + wave*512 + lane*8), 16,0,0); } }

    f32x4 acc[2][8];
    #pragma unroll
    for (int m=0;m<2;++m)
        #pragma unroll
        for (int j=0;j<8;++j)
            #pragma unroll
            for (int r=0;r<4;++r) acc[m][j][r] = 0.f;
    float l_l[2][4];
    #pragma unroll
    for (int m=0;m<2;++m){ l_l[m][0]=0.f; l_l[m][1]=0.f; l_l[m][2]=0.f; l_l[m][3]=0.f; }

    const bf16* KgJ = Kg;
    const bf16* VtJ = Vtb;

    STGQ;
    STGK(0, 0, KgJ);
    STGK(1, 1, KgJ);
    VM2; SCHED0; BAR;

    for (int jb=0; jb<njb; ++jb){
        const bool last = (jb == njb-1);
        f32x4 sacc[2][2];
        #pragma unroll
        for (int m=0;m<2;++m)
            #pragma unroll
            for (int nf=0;nf<2;++nf)
                #pragma unroll
                for (int r=0;r<4;++r) sacc[m][nf][r] = 0.f;

        #pragma unroll
        for (int ec=0; ec<8; ++ec){
            const int slot = ec%3;
            s16x8 qa[2][2], kb[2][2];
            #pragma unroll
            for (int m=0;m<2;++m)
                #pragma unroll
                for (int kk=0;kk<2;++kk){
                    const int row = wr*32 + m*16 + fr;
                    const int c = (ec*2+kk)*4 + fg;
                    qa[m][kk] = *(const s16x8*)(sQ + row*512 + ((c ^ (row&7))*8));
                }
            #pragma unroll
            for (int nf=0;nf<2;++nf)
                #pragma unroll
                for (int kk=0;kk<2;++kk){
                    const int row = wc*32 + nf*16 + fr;
                    const int c = kk*4 + fg;
                    kb[nf][kk] = *(const s16x8*)(sK + slot*8192 + row*64 + ((c ^ (row&7))*8));
                }
            if (ec < 6) STGK((ec+2)%3, ec+2, KgJ);
            PRIO1;
            #pragma unroll
            for (int m=0;m<2;++m)
                #pragma unroll
                for (int nf=0;nf<2;++nf)
                    #pragma unroll
                    for (int kk=0;kk<2;++kk)
                        sacc[m][nf] = __builtin_amdgcn_mfma_f32_16x16x32_bf16(qa[m][kk], kb[nf][kk], sacc[m][nf], 0,0,0);
            PRIO0;
            if (ec < 6) { VM2; } else if (ec == 6) { VM0; }
            SCHED0; BAR;
        }

        const int doff = (njb-1)*128 - ib*64;
        #pragma unroll
        for (int m=0;m<2;++m)
            #pragma unroll
            for (int nf=0;nf<2;++nf)
                #pragma unroll
                for (int r=0;r<4;++r){
                    float pv = __expf(sacc[m][nf][r]*SCALE - 4.0f);
                    const int rl = wr*32 + m*16 + fg*4 + r;
                    const int cl = wc*32 + nf*16 + fr;
                    if (last && (cl + doff > rl)) pv = 0.f;
                    sP[rl*128 + (((cl>>3) ^ (rl&15))*8) + (cl&7)] = f2b(pv);
                    l_l[m][r] += pv;
                }
        STGV(0, 0, 0, VtJ);
        if (!last){ STGK(0, 0, KgJ + 786432); STGK(1, 1, KgJ + 786432); }
        if (!last){ VM4; } else { VM0; }
        LGKM0; SCHED0; BAR;

        s16x8 pa[2];
        #pragma unroll
        for (int v=0; v<8; ++v){
            const int kf = v>>1, eh = v&1, buf = v&1;
            if (eh == 0){
                #pragma unroll
                for (int m=0;m<2;++m){
                    const int row = wr*32 + m*16 + fr;
                    const int c = kf*4 + fg;
                    pa[m] = *(const s16x8*)(sP + row*128 + ((c ^ (row&15))*8));
                }
            }
            s16x8 vb[4];
            #pragma unroll
            for (int nf=0;nf<4;++nf){
                const int row = wc*64 + nf*16 + fr;
                vb[nf] = *(const s16x8*)(sV + buf*8192 + row*32 + (((fg ^ ((row + (row>>2))&3)))*8));
            }
            if (v < 7) STGV((v+1)&1, (v+1)>>1, (v+1)&1, VtJ);
            PRIO1;
            #pragma unroll
            for (int m=0;m<2;++m)
                #pragma unroll
                for (int nf=0;nf<4;++nf)
                    acc[m][eh*4+nf] = __builtin_amdgcn_mfma_f32_16x16x32_bf16(pa[m], vb[nf], acc[m][eh*4+nf], 0,0,0);
            PRIO0;
            if (v < 7) { VM0; }
            SCHED0; BAR;
        }
        KgJ += 786432;
        VtJ += 128;
    }

    #pragma unroll
    for (int m=0;m<2;++m)
        #pragma unroll
        for (int r=0;r<4;++r){
            float v = l_l[m][r];
            v += __shfl_xor(v, 1); v += __shfl_xor(v, 2);
            v += __shfl_xor(v, 4); v += __shfl_xor(v, 8);
            l_l[m][r] = v;
        }
    if (fr == 0){
        #pragma unroll
        for (int m=0;m<2;++m)
            #pragma unroll
            for (int r=0;r<4;++r)
                part[(wr*32 + m*16 + fg*4 + r)*4 + wc] = l_l[m][r];
    }
    LGKM0; SCHED0; BAR;

    bf16* orow = outp + ((long)b*2048 + ib*64)*2048 + h*512;
    #pragma unroll
    for (int m=0;m<2;++m)
        #pragma unroll
        for (int r=0;r<4;++r){
            const int rl = wr*32 + m*16 + fg*4 + r;
            const f32x4 pp = *(const f32x4*)(part + rl*4);
            const float rinv = 1.f/(pp[0]+pp[1]+pp[2]+pp[3]);
            #pragma unroll
            for (int j=0;j<8;++j){
                const int e = (j>>2)*256 + wc*64 + (j&3)*16 + fr;
                orow[(long)rl*2048 + e] = f2b(acc[m][j][r]*rinv);
            }
        }
    #undef STGQ
    #undef STGK
    #undef STGV
}

// fp32 [Kd,Nd] -> bf16 [Nd,Kd]
__launch_bounds__(256)
__global__ void wtrans(const float* __restrict__ W, bf16* __restrict__ Wt, int Kd, int Nd){
    __shared__ float t[32][33];
    const int n0 = blockIdx.x*32, k0 = blockIdx.y*32;
    const int tx = threadIdx.x&31, ty = threadIdx.x>>5;
    #pragma unroll
    for (int i=0;i<32;i+=8) t[ty+i][tx] = W[(long)(k0+ty+i)*Nd + n0+tx];
    __syncthreads();
    #pragma unroll
    for (int i=0;i<32;i+=8) Wt[(long)(n0+ty+i)*Kd + k0+tx] = f2b(t[tx][ty+i]);
}

// x read ONCE: xb (bf16 cast) + out[:, :2048] concat copy
__launch_bounds__(256)
__global__ void xprep(const float* __restrict__ x, bf16* __restrict__ xb,
                      float* __restrict__ outp){
    const long idx = ((long)blockIdx.x*256 + threadIdx.x)*4;
    const float4 v = *(const float4*)&x[idx];
    B4 o; o.v[0]=f2b(v.x); o.v[1]=f2b(v.y); o.v[2]=f2b(v.z); o.v[3]=f2b(v.w);
    *reinterpret_cast<B4*>(&xb[idx]) = o;
    const long r = idx>>11, c = idx&2047;
    *(float4*)&outp[r*2560 + c] = v;
}

// LayerNorm over 2048-wide bf16 rows -> bf16.
__launch_bounds__(256)
__global__ void ln_rows(const bf16* __restrict__ inp, const float* __restrict__ gw,
                        const float* __restrict__ bw, bf16* __restrict__ outp){
    const long r = blockIdx.x;
    const int tid = threadIdx.x, k0 = tid*8;
    float v[8];
    const bf16* row = inp + r*2048;
    const B8 xv = *reinterpret_cast<const B8*>(&row[k0]);
    #pragma unroll
    for (int i=0;i<8;++i) v[i] = b2f(xv.v[i]);
    float s = 0.f, qq = 0.f;
    #pragma unroll
    for (int i=0;i<8;++i){ s += v[i]; qq += v[i]*v[i]; }
    #pragma unroll
    for (int o=32;o;o>>=1){ s += __shfl_xor(s,o); qq += __shfl_xor(qq,o); }
    __shared__ float s1[4], s2[4];
    if ((tid&63)==0){ s1[tid>>6]=s; s2[tid>>6]=qq; }
    __syncthreads();
    s  = s1[0]+s1[1]+s1[2]+s1[3];
    qq = s2[0]+s2[1]+s2[2]+s2[3];
    const float mean = s*(1.f/2048.f);
    const float var  = qq*(1.f/2048.f) - mean*mean;
    const float rinv = rsqrtf(var + 1e-5f);
    const float4 g1 = *(const float4*)&gw[k0];
    const float4 g2 = *(const float4*)&gw[k0+4];
    const float4 b1 = *(const float4*)&bw[k0];
    const float4 b2 = *(const float4*)&bw[k0+4];
    const float gg[8] = {g1.x,g1.y,g1.z,g1.w,g2.x,g2.y,g2.z,g2.w};
    const float bb[8] = {b1.x,b1.y,b1.z,b1.w,b2.x,b2.y,b2.z,b2.w};
    B8 o;
    #pragma unroll
    for (int i=0;i<8;++i) o.v[i] = f2b((v[i]-mean)*rinv*gg[i] + bb[i]);
    *reinterpret_cast<B8*>(&outp[r*2048 + k0]) = o;
}

extern "C" void kernel_launch(void* const* d_in, const int* in_sizes, int n_in,
                              void* d_out, int out_size, void* d_ws, size_t ws_size,
                              hipStream_t stream)
{
    (void)in_sizes; (void)n_in; (void)out_size;
    const float* x     = (const float*)d_in[0];
    const float* w_qkv = (const float*)d_in[1];
    const float* b_qkv = (const float*)d_in[2];
    const float* w_ao  = (const float*)d_in[3];
    const float* b_ao  = (const float*)d_in[4];
    const float* ln1g  = (const float*)d_in[5];
    const float* ln1b  = (const float*)d_in[6];
    const float* w_fc  = (const float*)d_in[7];
    const float* b_fc  = (const float*)d_in[8];
    const float* w_pr  = (const float*)d_in[9];
    const float* b_pr  = (const float*)d_in[10];
    const float* ln2g  = (const float*)d_in[11];
    const float* ln2b  = (const float*)d_in[12];
    const float* w_out = (const float*)d_in[13];
    const float* b_out = (const float*)d_in[14];
    float* out = (float*)d_out;
    char* ws = (char*)d_ws;

    const size_t NEEDED = 245366784ull;
    if (ws_size < NEEDED) return;

    bf16*  xb     = (bf16*)(ws);
    bf16*  qkv    = (bf16*)(ws + 33554432ull);
    bf16*  r1b    = (bf16*)(ws + 33554432ull);    // bf16 r1 (aliases dead qkv)
    bf16*  fcact  = (bf16*)(ws);
    float* kpart  = (float*)(ws);                 // phase 5: 4x[8192][512] f32 (67 MB)
    bf16*  vt     = (bf16*)(ws + 134217728ull);
    bf16*  Wfc_t  = (bf16*)(ws + 134217728ull);
    bf16*  rbufB  = (bf16*)(ws + 134217728ull);   // bf16 r2 [8192][2048]
    bf16*  Wpr_t  = (bf16*)(ws + 167772160ull);
    bf16*  Wqkv_t = (bf16*)(ws + 201326592ull);
    bf16*  nbuf   = (bf16*)(ws + 201326592ull);
    bf16*  Wao_t  = (bf16*)(ws + 234881024ull);
    bf16*  Wout_t = (bf16*)(ws + 243269632ull);

    const dim3 T(256);
    const int SMEM = 131072;
    const int SMEM_A = 163840;
    (void)hipFuncSetAttribute((const void*)gemm256<EPI_QKV>, hipFuncAttributeMaxDynamicSharedMemorySize, SMEM);
    (void)hipFuncSetAttribute((const void*)gemm256<EPI_AO>,  hipFuncAttributeMaxDynamicSharedMemorySize, SMEM);
    (void)hipFuncSetAttribute((const void*)gemm256<EPI_FC>,  hipFuncAttributeMaxDynamicSharedMemorySize, SMEM);
    (void)hipFuncSetAttribute((const void*)gemm256<EPI_PRB>, hipFuncAttributeMaxDynamicSharedMemorySize, SMEM);
    (void)hipFuncSetAttribute((const void*)gemm256<EPI_OUT>, hipFuncAttributeMaxDynamicSharedMemorySize, SMEM);
    (void)hipFuncSetAttribute((const void*)fattn,            hipFuncAttributeMaxDynamicSharedMemorySize, SMEM_A);

    // ---- phase 0: weight prep + x prep (xb cast + out concat, one x read) ----
    wtrans<<<dim3(192,64),T,0,stream>>>(w_qkv, Wqkv_t, 2048, 6144);
    wtrans<<<dim3(64,64), T,0,stream>>>(w_ao,  Wao_t,  2048, 2048);
    wtrans<<<dim3(16,64), T,0,stream>>>(w_out, Wout_t, 2048, 512);
    xprep<<<16384,T,0,stream>>>(x, xb, out);

    // ---- phase 1: qkv = x @ w_qkv + b_qkv; V-columns stored transposed into vt ----
    gemm256<EPI_QKV><<<dim3(768),dim3(512),SMEM,stream>>>(xb, Wqkv_t, qkv, b_qkv, vt,
        2048, 2048, 2048, 6144, 0, 24);

    // ---- phase 2: fused flash attention -> xb ----
    fattn<<<dim3(512),dim3(512),SMEM_A,stream>>>(qkv, vt, xb);

    // ---- phase 3: r1 = x + attn @ w_ao + b_ao (bf16), ln1 -> nbuf ----
    gemm256<EPI_AO><<<dim3(256),dim3(512),SMEM,stream>>>(xb, Wao_t, r1b, b_ao, x,
        2048, 2048, 2048, 2048, 2048, 8);
    ln_rows<<<8192,T,0,stream>>>(r1b, ln1g, ln1b, nbuf);

    // ---- phase 4: MLP ----
    wtrans<<<dim3(256,64),T,0,stream>>>(w_fc, Wfc_t, 2048, 8192);
    wtrans<<<dim3(64,256),T,0,stream>>>(w_pr, Wpr_t, 8192, 2048);
    gemm256<EPI_FC><<<dim3(1024),dim3(512),SMEM,stream>>>(nbuf, Wfc_t, fcact, b_fc, nullptr,
        2048, 2048, 2048, 8192, 0, 32);
    gemm256<EPI_PRB><<<dim3(256),dim3(512),SMEM,stream>>>(fcact, Wpr_t, rbufB, b_pr, nbuf,
        8192, 8192, 8192, 2048, 2048, 8);
    ln_rows<<<8192,T,0,stream>>>(rbufB, ln2g, ln2b, nbuf);

    // ---- phase 5: final head (split-K-4) + reduce ----
    gemm256<EPI_OUT><<<dim3(64,4),dim3(512),SMEM,stream>>>(nbuf, Wout_t, kpart, nullptr, nullptr,
        512, 2048, 2048, 512, 0, 2);
    kred<<<4096,T,0,stream>>>(kpart, b_out, out);
}